// Round 3
// baseline (54.559 us; speedup 1.0000x reference)
//
#include <hip/hip_runtime.h>

// Problem: out[a,j,r,b] = x[a,(d-j)%d,r,b] with d=4, index=2, L=6
// x: [N=4096, B=8192] float32 row-major. Row mapping:
//   src_row = row + delta*64, delta = {0,+2,0,-2}[(row>>6)&3].
// Pure permuted copy: 128 MiB read + 128 MiB write, memory-bound.
// R1: 45.96us @ 5.84 TB/s effective (93% of 6.3 TB/s).
// R3: nontemporal stores via native ext_vector_type (HIP_vector_type<float,4>
// is rejected by the builtin) + static unroll-16 for load MLP.

typedef float f32x4 __attribute__((ext_vector_type(4)));

#define B_COLS4  2048                  // B/4 float4 per row
#define LOG_B4   11                    // log2(2048)
#define N_ROWS   4096
#define TOTAL4   (N_ROWS * B_COLS4)    // 8,388,608 float4
#define NBLK     2048
#define NTHR     256
#define ITERS    (TOTAL4 / (NBLK * NTHR))   // = 16, exact

__global__ __launch_bounds__(NTHR) void perm_copy_kernel(
        const f32x4* __restrict__ x, f32x4* __restrict__ out) {
    const int stride = NBLK * NTHR;
    int n = blockIdx.x * NTHR + threadIdx.x;
#pragma unroll
    for (int it = 0; it < ITERS; ++it, n += stride) {
        int row = n >> LOG_B4;
        int col = n & (B_COLS4 - 1);
        int j   = (row >> 6) & 3;           // output wire digit
        int i   = (4 - j) & 3;              // source wire digit
        int src = ((row + ((i - j) << 6)) << LOG_B4) | col;
        f32x4 v = x[src];
        __builtin_nontemporal_store(v, &out[n]);
    }
}

extern "C" void kernel_launch(void* const* d_in, const int* in_sizes, int n_in,
                              void* d_out, int out_size, void* d_ws, size_t ws_size,
                              hipStream_t stream) {
    const f32x4* x   = (const f32x4*)d_in[0];
    f32x4*       out = (f32x4*)d_out;
    perm_copy_kernel<<<NBLK, NTHR, 0, stream>>>(x, out);
}

// Round 4
// 51.266 us; speedup vs baseline: 1.0642x; 1.0642x over previous
//
#include <hip/hip_runtime.h>

// Problem: out[a,j,r,b] = x[a,(d-j)%d,r,b] with d=4, index=2, L=6
// x: [N=4096, B=8192] float32 row-major. Row mapping:
//   src_row = row + delta*64, delta = {0,+2,0,-2}[(row>>6)&3].
// Pure permuted copy: 128 MiB read + 128 MiB write, memory-bound.
// R1: plain grid-stride, 45.96us (VGPR=4, 1 load in flight/thread).
// R3: +NT stores +unroll -> 54.6us REGRESSION (NT store path slower,
//     FETCH unchanged at 64MB -> NT doesn't protect L3 residency). Reverted.
// R4: unroll-16 ONLY (plain stores) -> 16 independent loads in flight.

typedef float f32x4 __attribute__((ext_vector_type(4)));

#define B_COLS4  2048                  // B/4 float4 per row
#define LOG_B4   11                    // log2(2048)
#define N_ROWS   4096
#define TOTAL4   (N_ROWS * B_COLS4)    // 8,388,608 float4
#define NBLK     2048
#define NTHR     256
#define ITERS    (TOTAL4 / (NBLK * NTHR))   // = 16, exact

__global__ __launch_bounds__(NTHR) void perm_copy_kernel(
        const f32x4* __restrict__ x, f32x4* __restrict__ out) {
    const int stride = NBLK * NTHR;
    int n = blockIdx.x * NTHR + threadIdx.x;
#pragma unroll
    for (int it = 0; it < ITERS; ++it, n += stride) {
        int row = n >> LOG_B4;
        int col = n & (B_COLS4 - 1);
        int j   = (row >> 6) & 3;           // output wire digit
        int i   = (4 - j) & 3;              // source wire digit
        int src = ((row + ((i - j) << 6)) << LOG_B4) | col;
        out[n] = x[src];
    }
}

extern "C" void kernel_launch(void* const* d_in, const int* in_sizes, int n_in,
                              void* d_out, int out_size, void* d_ws, size_t ws_size,
                              hipStream_t stream) {
    const f32x4* x   = (const f32x4*)d_in[0];
    f32x4*       out = (f32x4*)d_out;
    perm_copy_kernel<<<NBLK, NTHR, 0, stream>>>(x, out);
}

// Round 5
// 42.192 us; speedup vs baseline: 1.2931x; 1.2151x over previous
//
#include <hip/hip_runtime.h>

// Problem: out[a,j,r,b] = x[a,(d-j)%d,r,b] with d=4, index=2, L=6
// x: [N=4096, B=8192] float32 row-major. Row mapping:
//   src_row = row + delta*64, delta = {0,+2,0,-2}[(row>>6)&3].
// Pure permuted copy: 128 MiB read + 128 MiB write, memory-bound.
// R1: plain grid-stride x16, 45.96us = 5.84 TB/s apparent (93% of m13's
//     6.29 TB/s D2D copy ceiling). FETCH=64MB (L3 holds half the input).
// R3: NT stores + unroll -> 54.6us REGRESSION (NT store path slow, no L3 win).
// R4: unroll-16 alone    -> 51.3us REGRESSION (batched load/store schedule
//     worse than simple pipelined stream). Minimal R1 form is best.
// R5: flat launch, 1 float4/thread, no loop at all — purest copy structure.

typedef float f32x4 __attribute__((ext_vector_type(4)));

#define B_COLS4  2048                  // B/4 float4 per row
#define LOG_B4   11                    // log2(2048)
#define N_ROWS   4096
#define TOTAL4   (N_ROWS * B_COLS4)    // 8,388,608 float4
#define NTHR     256
#define NBLK     (TOTAL4 / NTHR)       // 32768 blocks, exact

__global__ __launch_bounds__(NTHR) void perm_copy_kernel(
        const f32x4* __restrict__ x, f32x4* __restrict__ out) {
    int n   = blockIdx.x * NTHR + threadIdx.x;
    int row = n >> LOG_B4;
    int j   = (row >> 6) & 3;           // output wire digit
    int i   = (4 - j) & 3;              // source wire digit
    out[n] = x[n + (((i - j) << 6) << LOG_B4)];
}

extern "C" void kernel_launch(void* const* d_in, const int* in_sizes, int n_in,
                              void* d_out, int out_size, void* d_ws, size_t ws_size,
                              hipStream_t stream) {
    const f32x4* x   = (const f32x4*)d_in[0];
    f32x4*       out = (f32x4*)d_out;
    perm_copy_kernel<<<NBLK, NTHR, 0, stream>>>(x, out);
}